// Round 4
// baseline (247.439 us; speedup 1.0000x reference)
//
#include <hip/hip_runtime.h>
#include <hip/hip_bf16.h>
#include <stdint.h>

// Problem constants (CompressedKVAttention_11708080848911)
#define Bc    4
#define Hc    32
#define HKVc  8
#define QLc   16
#define KVc   8192
#define Dc    128
#define NREPc 4   // H / HKV

typedef short bf16x8 __attribute__((ext_vector_type(8)));
typedef float f32x4  __attribute__((ext_vector_type(4)));
typedef int   i32x4  __attribute__((ext_vector_type(4)));
typedef unsigned short u16x4 __attribute__((ext_vector_type(4)));

__device__ __forceinline__ unsigned short bf16_rne(float f) {
  union { float f; uint32_t u; } c{f};
  uint32_t u = c.u + 0x7FFFu + ((c.u >> 16) & 1u);
  return (unsigned short)(u >> 16);
}
// exact for integer-valued floats in [0,255] (low 16 mantissa bits are zero)
__device__ __forceinline__ short bf16_exact(float f) {
  union { float f; uint32_t u; } c{f};
  return (short)(unsigned short)(c.u >> 16);
}

// ---------------------------------------------------------------------------
// Phase 1: per-(b,g,split) flash partials.
// KV caches arrive as INT32 (harness promotes integer inputs: "integer ->
// const int*"). R3: nsplit 16->64 (occupancy was 22%, grid-starved at 512
// blocks = 8 waves/CU; all pipes idle -> latency-bound). V staging retiled to
// 4 tokens x 4 d per thread with ds_write_b64 (was 16 scalar u16 writes).
//
// Block = 256 threads = 4 waves; wave w handles query head g*4+w (16 rows).
// K: global -> register B-frags (u = k+128, exact in bf16), QK via MFMA.
// V: staged per 32 tokens into LDS transposed [d][t] bf16 (v+128), token bits
//    3..4 XOR-swizzled by (d>>4)&3 to break bank conflicts.
// Scores: s_t*(dot_u - (z_t+128)*qsum_row), scale*log2e folded into s_t.
// Online-softmax max updated ONCE per 32-token block after both halves'
// scores are known (P in LDS always consistent with m used for acc/ell/corr).
// ---------------------------------------------------------------------------
__global__ __launch_bounds__(256, 6) void attn_partial(
    const float* __restrict__ q, const int* __restrict__ kc,
    const int* __restrict__ vc,
    const float* __restrict__ ksc, const float* __restrict__ kzr,
    const float* __restrict__ vsc, const float* __restrict__ vzr,
    float* __restrict__ ws_acc, float* __restrict__ ws_m,
    float* __restrict__ ws_l, int nsplit)
{
  __shared__ __align__(16) unsigned short Vlds[128][40]; // rows 80B (16B-aligned)
  __shared__ __align__(16) unsigned short Plds[4][16][40];

  const int bid   = blockIdx.x;
  const int split = bid % nsplit;
  const int bg    = bid / nsplit;          // 0..31  (= b*HKV + g)
  const int chunk = KVc / nsplit;
  const int t_begin = split * chunk;

  const int tid  = threadIdx.x;
  const int wave = tid >> 6;
  const int lane = tid & 63;
  const int l15  = lane & 15;
  const int lg   = lane >> 4;              // 0..3

  const int b = bg >> 3, g = bg & 7;
  const int h = (g << 2) + wave;           // this wave's query head

  // ---- Q fragments (bf16) + per-row sum of bf16-rounded Q ----
  bf16x8 qa[4];
  float qsum = 0.f;
  const float* qrow = q + ((size_t)((b * Hc + h) * QLc + l15)) * Dc;
#pragma unroll
  for (int ks = 0; ks < 4; ++ks) {
    const float* p = qrow + ks * 32 + (lg << 3);
    bf16x8 f;
#pragma unroll
    for (int j = 0; j < 8; ++j) {
      unsigned short hb = bf16_rne(p[j]);
      f[j] = (short)hb;
      union { uint32_t u; float ff; } w{(uint32_t)hb << 16};
      qsum += w.ff;                        // sum of post-rounding values
    }
    qa[ks] = f;
  }
  qsum += __shfl_xor(qsum, 16);
  qsum += __shfl_xor(qsum, 32);            // every lane: qsum of row (lane&15)
  float qsumc[4];                          // re-map to C-layout rows 4*lg+j
#pragma unroll
  for (int j = 0; j < 4; ++j) qsumc[j] = __shfl(qsum, (lg << 2) + j);

  const float QK_SCALE = 0.088388347648f * 1.44269504089f; // d^-1/2 * log2(e)

  float m[4], ell[4], corr[4];
  f32x4 acc[8];
#pragma unroll
  for (int j = 0; j < 4; ++j) { m[j] = -1e30f; ell[j] = 0.f; corr[j] = 0.f; }
#pragma unroll
  for (int dt = 0; dt < 8; ++dt) acc[dt] = (f32x4){0.f, 0.f, 0.f, 0.f};

  const int*   kb   = kc  + (size_t)bg * KVc * Dc;
  const int*   vb   = vc  + (size_t)bg * KVc * Dc;
  const float* kscb = ksc + (size_t)bg * KVc;
  const float* kzrb = kzr + (size_t)bg * KVc;
  const float* vscb = vsc + (size_t)bg * KVc;
  const float* vzrb = vzr + (size_t)bg * KVc;

  // staging coords (4 tokens x 4 d per thread)
  const int tq = tid >> 5;                 // 0..7 -> tokens 4*tq..4*tq+3
  const int dq = (tid & 31) << 2;          // 0,4,...,124
  const int swz = ((dq >> 4) & 3) << 3;    // XOR on token bits 3..4
  const int tb = (tq << 2) ^ swz;          // column base ((4tq+i)^swz = tb+i)

  for (int t0 = t_begin; t0 < t_begin + chunk; t0 += 32) {
    __syncthreads();
    { // ---- stage V: 32 tokens x 128 d, (v+128) bf16, transposed+swizzled ----
      i32x4 w[4];
#pragma unroll
      for (int i = 0; i < 4; ++i)
        w[i] = *(const i32x4*)(vb + (size_t)(t0 + (tq << 2) + i) * Dc + dq);
#pragma unroll
      for (int j = 0; j < 4; ++j) {
        u16x4 pk;
#pragma unroll
        for (int i = 0; i < 4; ++i)
          pk[i] = (unsigned short)bf16_exact((float)(w[i][j] + 128));
        *(u16x4*)&Vlds[dq + j][tb] = pk;
      }
    }
    __syncthreads();

    // ---- scores for BOTH halves (deferred max) ----
    float s8[2][4];
    float vsh[2], vzph[2];
#pragma unroll
    for (int half = 0; half < 2; ++half) {
      const int t = t0 + (half << 4) + l15;      // this lane's token (col)
      f32x4 sc = (f32x4){0.f, 0.f, 0.f, 0.f};
#pragma unroll
      for (int ks = 0; ks < 4; ++ks) {
        const int* kp = kb + (size_t)t * Dc + ks * 32 + (lg << 3);
        i32x4 a0 = *(const i32x4*)(kp);
        i32x4 a1 = *(const i32x4*)(kp + 4);
        bf16x8 kf;
#pragma unroll
        for (int j = 0; j < 4; ++j) {
          kf[j]     = bf16_exact((float)(a0[j] + 128));
          kf[4 + j] = bf16_exact((float)(a1[j] + 128));
        }
        sc = __builtin_amdgcn_mfma_f32_16x16x32_bf16(qa[ks], kf, sc, 0, 0, 0);
      }
      const float kscl = kscb[t] * QK_SCALE;
      const float kzp  = kzrb[t] + 128.f;
      vsh[half]  = vscb[t];
      vzph[half] = vzrb[t] + 128.f;
#pragma unroll
      for (int j = 0; j < 4; ++j)
        s8[half][j] = kscl * (sc[j] - kzp * qsumc[j]);
    }

    // ---- one max update + rescale per 32-token block ----
    float tm[4];
#pragma unroll
    for (int j = 0; j < 4; ++j) {
      tm[j] = fmaxf(s8[0][j], s8[1][j]);
      tm[j] = fmaxf(tm[j], __shfl_xor(tm[j], 1));
      tm[j] = fmaxf(tm[j], __shfl_xor(tm[j], 2));
      tm[j] = fmaxf(tm[j], __shfl_xor(tm[j], 4));
      tm[j] = fmaxf(tm[j], __shfl_xor(tm[j], 8));
    }
    bool need = false;
    float cf[4];
#pragma unroll
    for (int j = 0; j < 4; ++j) {
      float nm = fmaxf(m[j], tm[j]);
      cf[j] = exp2f(m[j] - nm);
      need = need || (tm[j] > m[j]);
      m[j] = nm;
    }
    if (__any(need)) {                     // wave-uniform rescale (rare later)
#pragma unroll
      for (int j = 0; j < 4; ++j) { ell[j] *= cf[j]; corr[j] *= cf[j]; }
#pragma unroll
      for (int dt = 0; dt < 8; ++dt)
#pragma unroll
        for (int j = 0; j < 4; ++j) acc[dt][j] *= cf[j];
    }

    // ---- P (consistent with final m) + fold value_scale; write Plds ----
#pragma unroll
    for (int half = 0; half < 2; ++half) {
#pragma unroll
      for (int j = 0; j < 4; ++j) {
        float p = exp2f(s8[half][j] - m[j]);
        ell[j] += p;
        unsigned short pb = bf16_rne(p * vsh[half]);
        union { uint32_t u; float ff; } pw{(uint32_t)pb << 16};
        corr[j] += pw.ff * vzph[half];     // use ROUNDED P' for consistency
        Plds[wave][(lg << 2) + j][(half << 4) + l15] = pb;
      }
    }

    // ---- PV for these 32 tokens ----
    bf16x8 pa = *(const bf16x8*)&Plds[wave][l15][lg << 3];
#pragma unroll
    for (int dt = 0; dt < 8; ++dt) {
      bf16x8 vbf = *(const bf16x8*)&Vlds[(dt << 4) + l15][(lg ^ (dt & 3)) << 3];
      acc[dt] = __builtin_amdgcn_mfma_f32_16x16x32_bf16(pa, vbf, acc[dt], 0, 0, 0);
    }
  }

  // ---- final lane reductions over token slots ----
#pragma unroll
  for (int j = 0; j < 4; ++j) {
    ell[j] += __shfl_xor(ell[j], 1);  ell[j] += __shfl_xor(ell[j], 2);
    ell[j] += __shfl_xor(ell[j], 4);  ell[j] += __shfl_xor(ell[j], 8);
    corr[j] += __shfl_xor(corr[j], 1); corr[j] += __shfl_xor(corr[j], 2);
    corr[j] += __shfl_xor(corr[j], 4); corr[j] += __shfl_xor(corr[j], 8);
  }

  const size_t pbase = ((size_t)bg * nsplit + split) * 64;
#pragma unroll
  for (int dt = 0; dt < 8; ++dt)
#pragma unroll
    for (int j = 0; j < 4; ++j) {
      int row = (wave << 4) + (lg << 2) + j;
      int d   = (dt << 4) + l15;
      ws_acc[(pbase + row) * Dc + d] = acc[dt][j] - corr[j];
    }
  if (l15 == 0) {
#pragma unroll
    for (int j = 0; j < 4; ++j) {
      int row = (wave << 4) + (lg << 2) + j;
      ws_m[pbase + row] = m[j];
      ws_l[pbase + row] = ell[j];
    }
  }
}

// ---------------------------------------------------------------------------
// Phase 2: flash-combine partials and normalize. One block per (bg,row).
// ---------------------------------------------------------------------------
__global__ __launch_bounds__(128) void attn_combine(
    const float* __restrict__ ws_acc, const float* __restrict__ ws_m,
    const float* __restrict__ ws_l, float* __restrict__ out, int nsplit)
{
  const int r   = blockIdx.x;      // 0 .. 32*64-1
  const int bg  = r >> 6;
  const int row = r & 63;
  const int d   = threadIdx.x;     // 0..127

  float M = -1e30f;
#pragma unroll 4
  for (int i = 0; i < nsplit; ++i)
    M = fmaxf(M, ws_m[((size_t)bg * nsplit + i) * 64 + row]);
  float L = 0.f, o = 0.f;
#pragma unroll 4
  for (int i = 0; i < nsplit; ++i) {
    size_t pb = ((size_t)bg * nsplit + i) * 64 + row;
    float w = exp2f(ws_m[pb] - M);
    L += ws_l[pb] * w;
    o += ws_acc[pb * Dc + d] * w;
  }
  const int b = bg >> 3, g = bg & 7;
  const int rep = row >> 4, qq = row & 15;
  out[(((size_t)(b * Hc + g * NREPc + rep)) * QLc + qq) * Dc + d] = o / L;
}

extern "C" void kernel_launch(void* const* d_in, const int* in_sizes, int n_in,
                              void* d_out, int out_size, void* d_ws,
                              size_t ws_size, hipStream_t stream) {
  const float* q   = (const float*)d_in[0];
  const int*   kc  = (const int*)d_in[1];   // int8 values promoted to int32
  const int*   vc  = (const int*)d_in[2];
  const float* ksc = (const float*)d_in[3];
  const float* kzr = (const float*)d_in[4];
  const float* vsc = (const float*)d_in[5];
  const float* vzr = (const float*)d_in[6];
  float* out = (float*)d_out;

  int nsplit = 64;                         // 2048 blocks; fallback if ws small
  while (nsplit > 1) {
    size_t need = (size_t)32 * nsplit * 64 * (Dc + 2) * sizeof(float);
    if (need <= ws_size) break;
    nsplit >>= 1;
  }
  float* ws_acc = (float*)d_ws;                             // [32,ns,64,128]
  float* ws_m   = ws_acc + (size_t)32 * nsplit * 64 * Dc;   // [32,ns,64]
  float* ws_l   = ws_m   + (size_t)32 * nsplit * 64;        // [32,ns,64]

  attn_partial<<<dim3(32 * nsplit), dim3(256), 0, stream>>>(
      q, kc, vc, ksc, kzr, vsc, vzr, ws_acc, ws_m, ws_l, nsplit);
  attn_combine<<<dim3(32 * 64), dim3(128), 0, stream>>>(
      ws_acc, ws_m, ws_l, out, nsplit);
}

// Round 5
// 163.707 us; speedup vs baseline: 1.5115x; 1.5115x over previous
//
#include <hip/hip_runtime.h>
#include <hip/hip_bf16.h>
#include <stdint.h>

// Problem constants (CompressedKVAttention_11708080848911)
#define Bc    4
#define Hc    32
#define HKVc  8
#define QLc   16
#define KVc   8192
#define Dc    128
#define NREPc 4   // H / HKV

typedef short bf16x8 __attribute__((ext_vector_type(8)));
typedef float f32x4  __attribute__((ext_vector_type(4)));
typedef int   i32x4  __attribute__((ext_vector_type(4)));
typedef unsigned short u16x4 __attribute__((ext_vector_type(4)));

__device__ __forceinline__ unsigned short bf16_rne(float f) {
  union { float f; uint32_t u; } c{f};
  uint32_t u = c.u + 0x7FFFu + ((c.u >> 16) & 1u);
  return (unsigned short)(u >> 16);
}
// exact for integer-valued floats in [0,255] (low 16 mantissa bits are zero)
__device__ __forceinline__ short bf16_exact(float f) {
  union { float f; uint32_t u; } c{f};
  return (short)(unsigned short)(c.u >> 16);
}

// ---------------------------------------------------------------------------
// Phase 1: per-(b,g,split) flash partials.
// KV caches arrive as INT32 (harness promotes integer inputs).
// R3 lesson: __launch_bounds__(256,6) forced VGPR 88->40 -> acc[] spilled to
// scratch -> WRITE_SIZE 16.6->353 MB, 247 us. R4 reverts to plain (256):
// natural 88 VGPR = 5 waves/SIMD, no spills. nsplit=64 (2048 blocks) kept --
// it raised occupancy 22->55%.
//
// Block = 256 threads = 4 waves; wave w handles query head g*4+w (16 rows).
// K: global -> register B-frags (u = k+128, exact in bf16), QK via MFMA.
// V: staged per 32 tokens into LDS transposed [d][t] bf16 (v+128), token bits
//    3..4 XOR-swizzled by (d>>4)&3 to break bank conflicts.
// Scores: s_t*(dot_u - (z_t+128)*qsum_row), scale*log2e folded into s_t.
// Online-softmax max updated ONCE per 32-token block after both halves'
// scores are known (P in LDS always consistent with m used for acc/ell/corr).
// ---------------------------------------------------------------------------
__global__ __launch_bounds__(256) void attn_partial(
    const float* __restrict__ q, const int* __restrict__ kc,
    const int* __restrict__ vc,
    const float* __restrict__ ksc, const float* __restrict__ kzr,
    const float* __restrict__ vsc, const float* __restrict__ vzr,
    float* __restrict__ ws_acc, float* __restrict__ ws_m,
    float* __restrict__ ws_l, int nsplit)
{
  __shared__ __align__(16) unsigned short Vlds[128][40]; // rows 80B (16B-aligned)
  __shared__ __align__(16) unsigned short Plds[4][16][40];

  const int bid   = blockIdx.x;
  const int split = bid % nsplit;
  const int bg    = bid / nsplit;          // 0..31  (= b*HKV + g)
  const int chunk = KVc / nsplit;
  const int t_begin = split * chunk;

  const int tid  = threadIdx.x;
  const int wave = tid >> 6;
  const int lane = tid & 63;
  const int l15  = lane & 15;
  const int lg   = lane >> 4;              // 0..3

  const int b = bg >> 3, g = bg & 7;
  const int h = (g << 2) + wave;           // this wave's query head

  // ---- Q fragments (bf16) + per-row sum of bf16-rounded Q ----
  bf16x8 qa[4];
  float qsum = 0.f;
  const float* qrow = q + ((size_t)((b * Hc + h) * QLc + l15)) * Dc;
#pragma unroll
  for (int ks = 0; ks < 4; ++ks) {
    const float* p = qrow + ks * 32 + (lg << 3);
    bf16x8 f;
#pragma unroll
    for (int j = 0; j < 8; ++j) {
      unsigned short hb = bf16_rne(p[j]);
      f[j] = (short)hb;
      union { uint32_t u; float ff; } w{(uint32_t)hb << 16};
      qsum += w.ff;                        // sum of post-rounding values
    }
    qa[ks] = f;
  }
  qsum += __shfl_xor(qsum, 16);
  qsum += __shfl_xor(qsum, 32);            // every lane: qsum of row (lane&15)
  float qsumc[4];                          // re-map to C-layout rows 4*lg+j
#pragma unroll
  for (int j = 0; j < 4; ++j) qsumc[j] = __shfl(qsum, (lg << 2) + j);

  const float QK_SCALE = 0.088388347648f * 1.44269504089f; // d^-1/2 * log2(e)

  float m[4], ell[4], corr[4];
  f32x4 acc[8];
#pragma unroll
  for (int j = 0; j < 4; ++j) { m[j] = -1e30f; ell[j] = 0.f; corr[j] = 0.f; }
#pragma unroll
  for (int dt = 0; dt < 8; ++dt) acc[dt] = (f32x4){0.f, 0.f, 0.f, 0.f};

  const int*   kb   = kc  + (size_t)bg * KVc * Dc;
  const int*   vb   = vc  + (size_t)bg * KVc * Dc;
  const float* kscb = ksc + (size_t)bg * KVc;
  const float* kzrb = kzr + (size_t)bg * KVc;
  const float* vscb = vsc + (size_t)bg * KVc;
  const float* vzrb = vzr + (size_t)bg * KVc;

  // staging coords (4 tokens x 4 d per thread)
  const int tq = tid >> 5;                 // 0..7 -> tokens 4*tq..4*tq+3
  const int dq = (tid & 31) << 2;          // 0,4,...,124
  const int swz = ((dq >> 4) & 3) << 3;    // XOR on token bits 3..4
  const int tb = (tq << 2) ^ swz;          // column base ((4tq+i)^swz = tb+i)

  for (int t0 = t_begin; t0 < t_begin + chunk; t0 += 32) {
    __syncthreads();
    { // ---- stage V: 32 tokens x 128 d, (v+128) bf16, transposed+swizzled ----
      i32x4 w[4];
#pragma unroll
      for (int i = 0; i < 4; ++i)
        w[i] = *(const i32x4*)(vb + (size_t)(t0 + (tq << 2) + i) * Dc + dq);
#pragma unroll
      for (int j = 0; j < 4; ++j) {
        u16x4 pk;
#pragma unroll
        for (int i = 0; i < 4; ++i)
          pk[i] = (unsigned short)bf16_exact((float)(w[i][j] + 128));
        *(u16x4*)&Vlds[dq + j][tb] = pk;
      }
    }
    __syncthreads();

    // ---- scores for BOTH halves (deferred max) ----
    float s8[2][4];
    float vsh[2], vzph[2];
#pragma unroll
    for (int half = 0; half < 2; ++half) {
      const int t = t0 + (half << 4) + l15;      // this lane's token (col)
      f32x4 sc = (f32x4){0.f, 0.f, 0.f, 0.f};
#pragma unroll
      for (int ks = 0; ks < 4; ++ks) {
        const int* kp = kb + (size_t)t * Dc + ks * 32 + (lg << 3);
        i32x4 a0 = *(const i32x4*)(kp);
        i32x4 a1 = *(const i32x4*)(kp + 4);
        bf16x8 kf;
#pragma unroll
        for (int j = 0; j < 4; ++j) {
          kf[j]     = bf16_exact((float)(a0[j] + 128));
          kf[4 + j] = bf16_exact((float)(a1[j] + 128));
        }
        sc = __builtin_amdgcn_mfma_f32_16x16x32_bf16(qa[ks], kf, sc, 0, 0, 0);
      }
      const float kscl = kscb[t] * QK_SCALE;
      const float kzp  = kzrb[t] + 128.f;
      vsh[half]  = vscb[t];
      vzph[half] = vzrb[t] + 128.f;
#pragma unroll
      for (int j = 0; j < 4; ++j)
        s8[half][j] = kscl * (sc[j] - kzp * qsumc[j]);
    }

    // ---- one max update + rescale per 32-token block ----
    float tm[4];
#pragma unroll
    for (int j = 0; j < 4; ++j) {
      tm[j] = fmaxf(s8[0][j], s8[1][j]);
      tm[j] = fmaxf(tm[j], __shfl_xor(tm[j], 1));
      tm[j] = fmaxf(tm[j], __shfl_xor(tm[j], 2));
      tm[j] = fmaxf(tm[j], __shfl_xor(tm[j], 4));
      tm[j] = fmaxf(tm[j], __shfl_xor(tm[j], 8));
    }
    bool need = false;
    float cf[4];
#pragma unroll
    for (int j = 0; j < 4; ++j) {
      float nm = fmaxf(m[j], tm[j]);
      cf[j] = exp2f(m[j] - nm);
      need = need || (tm[j] > m[j]);
      m[j] = nm;
    }
    if (__any(need)) {                     // wave-uniform rescale (rare later)
#pragma unroll
      for (int j = 0; j < 4; ++j) { ell[j] *= cf[j]; corr[j] *= cf[j]; }
#pragma unroll
      for (int dt = 0; dt < 8; ++dt)
#pragma unroll
        for (int j = 0; j < 4; ++j) acc[dt][j] *= cf[j];
    }

    // ---- P (consistent with final m) + fold value_scale; write Plds ----
#pragma unroll
    for (int half = 0; half < 2; ++half) {
#pragma unroll
      for (int j = 0; j < 4; ++j) {
        float p = exp2f(s8[half][j] - m[j]);
        ell[j] += p;
        unsigned short pb = bf16_rne(p * vsh[half]);
        union { uint32_t u; float ff; } pw{(uint32_t)pb << 16};
        corr[j] += pw.ff * vzph[half];     // use ROUNDED P' for consistency
        Plds[wave][(lg << 2) + j][(half << 4) + l15] = pb;
      }
    }

    // ---- PV for these 32 tokens ----
    bf16x8 pa = *(const bf16x8*)&Plds[wave][l15][lg << 3];
#pragma unroll
    for (int dt = 0; dt < 8; ++dt) {
      bf16x8 vbf = *(const bf16x8*)&Vlds[(dt << 4) + l15][(lg ^ (dt & 3)) << 3];
      acc[dt] = __builtin_amdgcn_mfma_f32_16x16x32_bf16(pa, vbf, acc[dt], 0, 0, 0);
    }
  }

  // ---- final lane reductions over token slots ----
#pragma unroll
  for (int j = 0; j < 4; ++j) {
    ell[j] += __shfl_xor(ell[j], 1);  ell[j] += __shfl_xor(ell[j], 2);
    ell[j] += __shfl_xor(ell[j], 4);  ell[j] += __shfl_xor(ell[j], 8);
    corr[j] += __shfl_xor(corr[j], 1); corr[j] += __shfl_xor(corr[j], 2);
    corr[j] += __shfl_xor(corr[j], 4); corr[j] += __shfl_xor(corr[j], 8);
  }

  const size_t pbase = ((size_t)bg * nsplit + split) * 64;
#pragma unroll
  for (int dt = 0; dt < 8; ++dt)
#pragma unroll
    for (int j = 0; j < 4; ++j) {
      int row = (wave << 4) + (lg << 2) + j;
      int d   = (dt << 4) + l15;
      ws_acc[(pbase + row) * Dc + d] = acc[dt][j] - corr[j];
    }
  if (l15 == 0) {
#pragma unroll
    for (int j = 0; j < 4; ++j) {
      int row = (wave << 4) + (lg << 2) + j;
      ws_m[pbase + row] = m[j];
      ws_l[pbase + row] = ell[j];
    }
  }
}

// ---------------------------------------------------------------------------
// Phase 2: flash-combine partials and normalize. One block per (bg,row).
// ---------------------------------------------------------------------------
__global__ __launch_bounds__(128) void attn_combine(
    const float* __restrict__ ws_acc, const float* __restrict__ ws_m,
    const float* __restrict__ ws_l, float* __restrict__ out, int nsplit)
{
  const int r   = blockIdx.x;      // 0 .. 32*64-1
  const int bg  = r >> 6;
  const int row = r & 63;
  const int d   = threadIdx.x;     // 0..127

  float M = -1e30f;
#pragma unroll 4
  for (int i = 0; i < nsplit; ++i)
    M = fmaxf(M, ws_m[((size_t)bg * nsplit + i) * 64 + row]);
  float L = 0.f, o = 0.f;
#pragma unroll 4
  for (int i = 0; i < nsplit; ++i) {
    size_t pb = ((size_t)bg * nsplit + i) * 64 + row;
    float w = exp2f(ws_m[pb] - M);
    L += ws_l[pb] * w;
    o += ws_acc[pb * Dc + d] * w;
  }
  const int b = bg >> 3, g = bg & 7;
  const int rep = row >> 4, qq = row & 15;
  out[(((size_t)(b * Hc + g * NREPc + rep)) * QLc + qq) * Dc + d] = o / L;
}

extern "C" void kernel_launch(void* const* d_in, const int* in_sizes, int n_in,
                              void* d_out, int out_size, void* d_ws,
                              size_t ws_size, hipStream_t stream) {
  const float* q   = (const float*)d_in[0];
  const int*   kc  = (const int*)d_in[1];   // int8 values promoted to int32
  const int*   vc  = (const int*)d_in[2];
  const float* ksc = (const float*)d_in[3];
  const float* kzr = (const float*)d_in[4];
  const float* vsc = (const float*)d_in[5];
  const float* vzr = (const float*)d_in[6];
  float* out = (float*)d_out;

  int nsplit = 64;                         // 2048 blocks; fallback if ws small
  while (nsplit > 1) {
    size_t need = (size_t)32 * nsplit * 64 * (Dc + 2) * sizeof(float);
    if (need <= ws_size) break;
    nsplit >>= 1;
  }
  float* ws_acc = (float*)d_ws;                             // [32,ns,64,128]
  float* ws_m   = ws_acc + (size_t)32 * nsplit * 64 * Dc;   // [32,ns,64]
  float* ws_l   = ws_m   + (size_t)32 * nsplit * 64;        // [32,ns,64]

  attn_partial<<<dim3(32 * nsplit), dim3(256), 0, stream>>>(
      q, kc, vc, ksc, kzr, vsc, vzr, ws_acc, ws_m, ws_l, nsplit);
  attn_combine<<<dim3(32 * 64), dim3(128), 0, stream>>>(
      ws_acc, ws_m, ws_l, out, nsplit);
}

// Round 6
// 160.321 us; speedup vs baseline: 1.5434x; 1.0211x over previous
//
#include <hip/hip_runtime.h>
#include <hip/hip_bf16.h>
#include <stdint.h>

// Problem constants (CompressedKVAttention_11708080848911)
#define Bc    4
#define Hc    32
#define HKVc  8
#define QLc   16
#define KVc   8192
#define Dc    128
#define NREPc 4   // H / HKV

typedef short bf16x8 __attribute__((ext_vector_type(8)));
typedef float f32x4  __attribute__((ext_vector_type(4)));
typedef int   i32x4  __attribute__((ext_vector_type(4)));
typedef unsigned short u16x4 __attribute__((ext_vector_type(4)));

__device__ __forceinline__ unsigned short bf16_rne(float f) {
  union { float f; uint32_t u; } c{f};
  uint32_t u = c.u + 0x7FFFu + ((c.u >> 16) & 1u);
  return (unsigned short)(u >> 16);
}
// exact for integer-valued floats in [0,255] (low 16 mantissa bits are zero)
__device__ __forceinline__ short bf16_exact(float f) {
  union { float f; uint32_t u; } c{f};
  return (short)(unsigned short)(c.u >> 16);
}

// ---------------------------------------------------------------------------
// Phase 1: per-(b,g,split) flash partials. KV caches arrive as INT32.
// R5: latency-bound fix (R4: occ 31%, VALU 21%, Mfma 2%, 0.9 TB/s).
//  - K now staged to LDS once per block (was: each of 4 waves re-loaded the
//    same K tile from global -> 4x L2 traffic + exposed latency + 4x unpack).
//    Layout Klds[32][128] bf16, XOR swizzle si = d ^ ((t&7)<<3) on BOTH
//    write and read (same involution).
//  - 2-phase software pipeline per 32-token tile: issue next tile's K+V
//    global->reg loads, compute current tile from LDS, convert+write next
//    tile to the alternate LDS buffer (vmcnt wait lands after compute ->
//    HBM latency hidden), ONE barrier per tile.
//  - V pad 40->32 cols (swizzle handles banks); LDS 37.1KB = 4 blocks/CU.
//  - launch_bounds(256,4): VGPR cap 128 >= ~110 need (R3 lesson: cap 85
//    caused acc spill catastrophe; this cap is above natural need).
// ---------------------------------------------------------------------------
__global__ __launch_bounds__(256, 4) void attn_partial(
    const float* __restrict__ q, const int* __restrict__ kc,
    const int* __restrict__ vc,
    const float* __restrict__ ksc, const float* __restrict__ kzr,
    const float* __restrict__ vsc, const float* __restrict__ vzr,
    float* __restrict__ ws_acc, float* __restrict__ ws_m,
    float* __restrict__ ws_l, int nsplit)
{
  __shared__ __align__(16) unsigned short Klds[2][32][128];
  __shared__ __align__(16) unsigned short Vlds[2][128][32];
  __shared__ __align__(16) unsigned short Plds[4][16][40];

  const int bid   = blockIdx.x;
  const int split = bid % nsplit;
  const int bg    = bid / nsplit;          // 0..31  (= b*HKV + g)
  const int chunk = KVc / nsplit;
  const int t_begin = split * chunk;
  const int nt    = chunk >> 5;            // 32-token tiles

  const int tid  = threadIdx.x;
  const int wave = tid >> 6;
  const int lane = tid & 63;
  const int l15  = lane & 15;
  const int lg   = lane >> 4;              // 0..3

  const int b = bg >> 3, g = bg & 7;
  const int h = (g << 2) + wave;           // this wave's query head

  // ---- Q fragments (bf16) + per-row sum of bf16-rounded Q ----
  bf16x8 qa[4];
  float qsum = 0.f;
  const float* qrow = q + ((size_t)((b * Hc + h) * QLc + l15)) * Dc;
#pragma unroll
  for (int ks = 0; ks < 4; ++ks) {
    const float* p = qrow + ks * 32 + (lg << 3);
    bf16x8 f;
#pragma unroll
    for (int j = 0; j < 8; ++j) {
      unsigned short hb = bf16_rne(p[j]);
      f[j] = (short)hb;
      union { uint32_t u; float ff; } w{(uint32_t)hb << 16};
      qsum += w.ff;                        // sum of post-rounding values
    }
    qa[ks] = f;
  }
  qsum += __shfl_xor(qsum, 16);
  qsum += __shfl_xor(qsum, 32);            // every lane: qsum of row (lane&15)
  float qsumc[4];                          // re-map to C-layout rows 4*lg+j
#pragma unroll
  for (int j = 0; j < 4; ++j) qsumc[j] = __shfl(qsum, (lg << 2) + j);

  const float QK_SCALE = 0.088388347648f * 1.44269504089f; // d^-1/2 * log2(e)

  float m[4], ell[4], corr[4];
  f32x4 acc[8];
#pragma unroll
  for (int j = 0; j < 4; ++j) { m[j] = -1e30f; ell[j] = 0.f; corr[j] = 0.f; }
#pragma unroll
  for (int dt = 0; dt < 8; ++dt) acc[dt] = (f32x4){0.f, 0.f, 0.f, 0.f};

  const int*   kb   = kc  + (size_t)bg * KVc * Dc;
  const int*   vb   = vc  + (size_t)bg * KVc * Dc;
  const float* kscb = ksc + (size_t)bg * KVc;
  const float* kzrb = kzr + (size_t)bg * KVc;
  const float* vscb = vsc + (size_t)bg * KVc;
  const float* vzrb = vzr + (size_t)bg * KVc;

  // staging coords
  const int kt  = tid >> 3;                // K: token 0..31
  const int kd  = (tid & 7) << 4;          // K: d base 0,16,...,112
  const int ksw = (kt & 7) << 3;           // K row swizzle (short-index XOR)
  const int tq  = tid >> 5;                // V: token group 0..7
  const int dq  = (tid & 31) << 2;         // V: d base 0,4,...,124
  const int tb  = (tq << 2) ^ ((((dq >> 4) & 3)) << 3);  // swizzled col base

  i32x4 kpre[4], vpre[4];                  // prefetch registers (next tile)

  auto load_tile = [&](int t0) {
    const int* ksrc = kb + (size_t)(t0 + kt) * Dc + kd;
#pragma unroll
    for (int i = 0; i < 4; ++i) kpre[i] = ((const i32x4*)ksrc)[i];
#pragma unroll
    for (int i = 0; i < 4; ++i)
      vpre[i] = *(const i32x4*)(vb + (size_t)(t0 + (tq << 2) + i) * Dc + dq);
  };
  auto write_tile = [&](int buf) {
    bf16x8 k0, k1;
#pragma unroll
    for (int j = 0; j < 4; ++j) {
      k0[j]     = bf16_exact((float)(kpre[0][j] + 128));
      k0[4 + j] = bf16_exact((float)(kpre[1][j] + 128));
      k1[j]     = bf16_exact((float)(kpre[2][j] + 128));
      k1[4 + j] = bf16_exact((float)(kpre[3][j] + 128));
    }
    *(bf16x8*)&Klds[buf][kt][kd ^ ksw]       = k0;
    *(bf16x8*)&Klds[buf][kt][(kd + 8) ^ ksw] = k1;
#pragma unroll
    for (int j = 0; j < 4; ++j) {
      u16x4 pk;
#pragma unroll
      for (int i = 0; i < 4; ++i)
        pk[i] = (unsigned short)bf16_exact((float)(vpre[i][j] + 128));
      *(u16x4*)&Vlds[buf][dq + j][tb] = pk;
    }
  };

  // prologue: tile 0 into buffer 0
  load_tile(t_begin);
  write_tile(0);
  __syncthreads();
  int cur = 0;

  for (int it = 0; it < nt; ++it) {
    const int t0 = t_begin + (it << 5);
    if (it + 1 < nt) load_tile(t0 + 32);   // async: consumed after compute

    // ---- compute tile from LDS[cur] ----
    // hoisted scale loads (overlap with MFMA chain)
    const int tA = t0 + l15, tB = t0 + 16 + l15;
    const float ksA = kscb[tA], kzA = kzrb[tA], vsA = vscb[tA], vzA = vzrb[tA];
    const float ksB = kscb[tB], kzB = kzrb[tB], vsB = vscb[tB], vzB = vzrb[tB];

    f32x4 scA = (f32x4){0.f, 0.f, 0.f, 0.f};
    f32x4 scB = (f32x4){0.f, 0.f, 0.f, 0.f};
#pragma unroll
    for (int ks = 0; ks < 4; ++ks) {
      bf16x8 kfA = *(const bf16x8*)
          &Klds[cur][l15][(ks * 32 + (lg << 3)) ^ ((l15 & 7) << 3)];
      scA = __builtin_amdgcn_mfma_f32_16x16x32_bf16(qa[ks], kfA, scA, 0, 0, 0);
    }
#pragma unroll
    for (int ks = 0; ks < 4; ++ks) {
      bf16x8 kfB = *(const bf16x8*)
          &Klds[cur][16 + l15][(ks * 32 + (lg << 3)) ^ ((l15 & 7) << 3)];
      scB = __builtin_amdgcn_mfma_f32_16x16x32_bf16(qa[ks], kfB, scB, 0, 0, 0);
    }

    float s8[2][4];
    const float sclA = ksA * QK_SCALE, kzpA = kzA + 128.f;
    const float sclB = ksB * QK_SCALE, kzpB = kzB + 128.f;
#pragma unroll
    for (int j = 0; j < 4; ++j) {
      s8[0][j] = sclA * (scA[j] - kzpA * qsumc[j]);
      s8[1][j] = sclB * (scB[j] - kzpB * qsumc[j]);
    }

    // one max update + rescale per 32-token tile
    float tm[4];
#pragma unroll
    for (int j = 0; j < 4; ++j) {
      tm[j] = fmaxf(s8[0][j], s8[1][j]);
      tm[j] = fmaxf(tm[j], __shfl_xor(tm[j], 1));
      tm[j] = fmaxf(tm[j], __shfl_xor(tm[j], 2));
      tm[j] = fmaxf(tm[j], __shfl_xor(tm[j], 4));
      tm[j] = fmaxf(tm[j], __shfl_xor(tm[j], 8));
    }
    bool need = false;
    float cf[4];
#pragma unroll
    for (int j = 0; j < 4; ++j) {
      float nm = fmaxf(m[j], tm[j]);
      cf[j] = exp2f(m[j] - nm);
      need = need || (tm[j] > m[j]);
      m[j] = nm;
    }
    if (__any(need)) {
#pragma unroll
      for (int j = 0; j < 4; ++j) { ell[j] *= cf[j]; corr[j] *= cf[j]; }
#pragma unroll
      for (int dt = 0; dt < 8; ++dt)
#pragma unroll
        for (int j = 0; j < 4; ++j) acc[dt][j] *= cf[j];
    }

    // P (consistent with final m), value_scale folded; write Plds
#pragma unroll
    for (int j = 0; j < 4; ++j) {
      float pA = exp2f(s8[0][j] - m[j]);
      float pB = exp2f(s8[1][j] - m[j]);
      ell[j] += pA + pB;
      unsigned short ra = bf16_rne(pA * vsA);
      unsigned short rb = bf16_rne(pB * vsB);
      union { uint32_t u; float ff; } wa{(uint32_t)ra << 16}, wb{(uint32_t)rb << 16};
      corr[j] += wa.ff * (vzA + 128.f) + wb.ff * (vzB + 128.f);
      Plds[wave][(lg << 2) + j][l15]      = ra;
      Plds[wave][(lg << 2) + j][16 + l15] = rb;
    }

    // PV for these 32 tokens
    bf16x8 pa = *(const bf16x8*)&Plds[wave][l15][lg << 3];
#pragma unroll
    for (int dt = 0; dt < 8; ++dt) {
      bf16x8 vbf = *(const bf16x8*)
          &Vlds[cur][(dt << 4) + l15][(lg ^ (dt & 3)) << 3];
      acc[dt] = __builtin_amdgcn_mfma_f32_16x16x32_bf16(pa, vbf, acc[dt], 0, 0, 0);
    }

    // ---- stage next tile into LDS[cur^1]; one barrier per tile ----
    if (it + 1 < nt) {
      write_tile(cur ^ 1);                 // waits vmcnt for its own loads
      __syncthreads();
      cur ^= 1;
    }
  }

  // ---- final lane reductions over token slots ----
#pragma unroll
  for (int j = 0; j < 4; ++j) {
    ell[j] += __shfl_xor(ell[j], 1);  ell[j] += __shfl_xor(ell[j], 2);
    ell[j] += __shfl_xor(ell[j], 4);  ell[j] += __shfl_xor(ell[j], 8);
    corr[j] += __shfl_xor(corr[j], 1); corr[j] += __shfl_xor(corr[j], 2);
    corr[j] += __shfl_xor(corr[j], 4); corr[j] += __shfl_xor(corr[j], 8);
  }

  const size_t pbase = ((size_t)bg * nsplit + split) * 64;
#pragma unroll
  for (int dt = 0; dt < 8; ++dt)
#pragma unroll
    for (int j = 0; j < 4; ++j) {
      int row = (wave << 4) + (lg << 2) + j;
      int d   = (dt << 4) + l15;
      ws_acc[(pbase + row) * Dc + d] = acc[dt][j] - corr[j];
    }
  if (l15 == 0) {
#pragma unroll
    for (int j = 0; j < 4; ++j) {
      int row = (wave << 4) + (lg << 2) + j;
      ws_m[pbase + row] = m[j];
      ws_l[pbase + row] = ell[j];
    }
  }
}

// ---------------------------------------------------------------------------
// Phase 2: flash-combine partials and normalize. One block per (bg,row).
// ---------------------------------------------------------------------------
__global__ __launch_bounds__(128) void attn_combine(
    const float* __restrict__ ws_acc, const float* __restrict__ ws_m,
    const float* __restrict__ ws_l, float* __restrict__ out, int nsplit)
{
  const int r   = blockIdx.x;      // 0 .. 32*64-1
  const int bg  = r >> 6;
  const int row = r & 63;
  const int d   = threadIdx.x;     // 0..127

  float M = -1e30f;
#pragma unroll 4
  for (int i = 0; i < nsplit; ++i)
    M = fmaxf(M, ws_m[((size_t)bg * nsplit + i) * 64 + row]);
  float L = 0.f, o = 0.f;
#pragma unroll 4
  for (int i = 0; i < nsplit; ++i) {
    size_t pb = ((size_t)bg * nsplit + i) * 64 + row;
    float w = exp2f(ws_m[pb] - M);
    L += ws_l[pb] * w;
    o += ws_acc[pb * Dc + d] * w;
  }
  const int b = bg >> 3, g = bg & 7;
  const int rep = row >> 4, qq = row & 15;
  out[(((size_t)(b * Hc + g * NREPc + rep)) * QLc + qq) * Dc + d] = o / L;
}

extern "C" void kernel_launch(void* const* d_in, const int* in_sizes, int n_in,
                              void* d_out, int out_size, void* d_ws,
                              size_t ws_size, hipStream_t stream) {
  const float* q   = (const float*)d_in[0];
  const int*   kc  = (const int*)d_in[1];   // int8 values promoted to int32
  const int*   vc  = (const int*)d_in[2];
  const float* ksc = (const float*)d_in[3];
  const float* kzr = (const float*)d_in[4];
  const float* vsc = (const float*)d_in[5];
  const float* vzr = (const float*)d_in[6];
  float* out = (float*)d_out;

  int nsplit = 64;                         // 2048 blocks; fallback if ws small
  while (nsplit > 1) {
    size_t need = (size_t)32 * nsplit * 64 * (Dc + 2) * sizeof(float);
    if (need <= ws_size) break;
    nsplit >>= 1;
  }
  float* ws_acc = (float*)d_ws;                             // [32,ns,64,128]
  float* ws_m   = ws_acc + (size_t)32 * nsplit * 64 * Dc;   // [32,ns,64]
  float* ws_l   = ws_m   + (size_t)32 * nsplit * 64;        // [32,ns,64]

  attn_partial<<<dim3(32 * nsplit), dim3(256), 0, stream>>>(
      q, kc, vc, ksc, kzr, vsc, vzr, ws_acc, ws_m, ws_l, nsplit);
  attn_combine<<<dim3(32 * 64), dim3(128), 0, stream>>>(
      ws_acc, ws_m, ws_l, out, nsplit);
}

// Round 7
// 112.875 us; speedup vs baseline: 2.1922x; 1.4203x over previous
//
#include <hip/hip_runtime.h>
#include <hip/hip_bf16.h>
#include <stdint.h>

// Problem constants (CompressedKVAttention_11708080848911)
#define Bc    4
#define Hc    32
#define HKVc  8
#define QLc   16
#define KVc   8192
#define Dc    128
#define NREPc 4   // H / HKV

typedef short bf16x8 __attribute__((ext_vector_type(8)));
typedef float f32x4  __attribute__((ext_vector_type(4)));
typedef int   i32x4  __attribute__((ext_vector_type(4)));
typedef unsigned short u16x4 __attribute__((ext_vector_type(4)));

__device__ __forceinline__ unsigned short bf16_rne(float f) {
  union { float f; uint32_t u; } c{f};
  uint32_t u = c.u + 0x7FFFu + ((c.u >> 16) & 1u);
  return (unsigned short)(u >> 16);
}
// exact for integer-valued floats in [0,255] (low 16 mantissa bits are zero)
__device__ __forceinline__ short bf16_exact(float f) {
  union { float f; uint32_t u; } c{f};
  return (short)(unsigned short)(c.u >> 16);
}

// ---------------------------------------------------------------------------
// Phase 1: per-(b,g,split) flash partials. KV caches arrive as INT32.
// R6: R5's pipeline was sound but lambdas + launch_bounds(256,4) spilled the
// prefetch/acc state to scratch (VGPR 64, WRITE 229MB). This round: staging
// fully inlined (no lambdas; arrays only with unrolled const indices) and
// plain launch_bounds(256) -> natural VGPR allocation, zero scratch.
// Structure per 32-token tile:
//   issue next tile's K+V global->reg loads   (vmcnt wait lands after compute)
//   compute current tile from LDS[cur]        (QK MFMA, softmax, PV MFMA)
//   convert+write next tile into LDS[cur^1]; one __syncthreads per tile.
// K staged once per block (4 waves share it); XOR swizzle d^((t&7)<<3) on
// both write and read. V transposed [d][t], token bits 3..4 XOR (d>>4)&3.
// ---------------------------------------------------------------------------
__global__ __launch_bounds__(256) void attn_partial(
    const float* __restrict__ q, const int* __restrict__ kc,
    const int* __restrict__ vc,
    const float* __restrict__ ksc, const float* __restrict__ kzr,
    const float* __restrict__ vsc, const float* __restrict__ vzr,
    float* __restrict__ ws_acc, float* __restrict__ ws_m,
    float* __restrict__ ws_l, int nsplit)
{
  __shared__ __align__(16) unsigned short Klds[2][32][128];
  __shared__ __align__(16) unsigned short Vlds[2][128][32];
  __shared__ __align__(16) unsigned short Plds[4][16][40];

  const int bid   = blockIdx.x;
  const int split = bid % nsplit;
  const int bg    = bid / nsplit;          // 0..31  (= b*HKV + g)
  const int chunk = KVc / nsplit;
  const int t_begin = split * chunk;
  const int nt    = chunk >> 5;            // 32-token tiles

  const int tid  = threadIdx.x;
  const int wave = tid >> 6;
  const int lane = tid & 63;
  const int l15  = lane & 15;
  const int lg   = lane >> 4;              // 0..3

  const int b = bg >> 3, g = bg & 7;
  const int h = (g << 2) + wave;           // this wave's query head

  // ---- Q fragments (bf16) + per-row sum of bf16-rounded Q ----
  bf16x8 qa[4];
  float qsum = 0.f;
  const float* qrow = q + ((size_t)((b * Hc + h) * QLc + l15)) * Dc;
#pragma unroll
  for (int ks = 0; ks < 4; ++ks) {
    const float* p = qrow + ks * 32 + (lg << 3);
    bf16x8 f;
#pragma unroll
    for (int j = 0; j < 8; ++j) {
      unsigned short hb = bf16_rne(p[j]);
      f[j] = (short)hb;
      union { uint32_t u; float ff; } w{(uint32_t)hb << 16};
      qsum += w.ff;                        // sum of post-rounding values
    }
    qa[ks] = f;
  }
  qsum += __shfl_xor(qsum, 16);
  qsum += __shfl_xor(qsum, 32);            // every lane: qsum of row (lane&15)
  float qsumc[4];                          // re-map to C-layout rows 4*lg+j
#pragma unroll
  for (int j = 0; j < 4; ++j) qsumc[j] = __shfl(qsum, (lg << 2) + j);

  const float QK_SCALE = 0.088388347648f * 1.44269504089f; // d^-1/2 * log2(e)

  float m[4], ell[4], corr[4];
  f32x4 acc[8];
#pragma unroll
  for (int j = 0; j < 4; ++j) { m[j] = -1e30f; ell[j] = 0.f; corr[j] = 0.f; }
#pragma unroll
  for (int dt = 0; dt < 8; ++dt) acc[dt] = (f32x4){0.f, 0.f, 0.f, 0.f};

  const int*   kb   = kc  + (size_t)bg * KVc * Dc;
  const int*   vb   = vc  + (size_t)bg * KVc * Dc;
  const float* kscb = ksc + (size_t)bg * KVc;
  const float* kzrb = kzr + (size_t)bg * KVc;
  const float* vscb = vsc + (size_t)bg * KVc;
  const float* vzrb = vzr + (size_t)bg * KVc;

  // staging coords
  const int kt  = tid >> 3;                // K: token 0..31
  const int kd  = (tid & 7) << 4;          // K: d base 0,16,...,112
  const int ksw = (kt & 7) << 3;           // K row swizzle (short-index XOR)
  const int tq  = tid >> 5;                // V: token group 0..7
  const int dq  = (tid & 31) << 2;         // V: d base 0,4,...,124
  const int tb  = (tq << 2) ^ ((((dq >> 4) & 3)) << 3);  // swizzled col base

  // ---- prologue: stage tile 0 into buffer 0 (inline, no lambdas) ----
  {
    const int* ksrc = kb + (size_t)(t_begin + kt) * Dc + kd;
    i32x4 kp[4];
#pragma unroll
    for (int i = 0; i < 4; ++i) kp[i] = ((const i32x4*)ksrc)[i];
    i32x4 vp[4];
#pragma unroll
    for (int i = 0; i < 4; ++i)
      vp[i] = *(const i32x4*)(vb + (size_t)(t_begin + (tq << 2) + i) * Dc + dq);

    bf16x8 k0, k1;
#pragma unroll
    for (int j = 0; j < 4; ++j) {
      k0[j]     = bf16_exact((float)(kp[0][j] + 128));
      k0[4 + j] = bf16_exact((float)(kp[1][j] + 128));
      k1[j]     = bf16_exact((float)(kp[2][j] + 128));
      k1[4 + j] = bf16_exact((float)(kp[3][j] + 128));
    }
    *(bf16x8*)&Klds[0][kt][kd ^ ksw]       = k0;
    *(bf16x8*)&Klds[0][kt][(kd + 8) ^ ksw] = k1;
#pragma unroll
    for (int j = 0; j < 4; ++j) {
      u16x4 pk;
#pragma unroll
      for (int i = 0; i < 4; ++i)
        pk[i] = (unsigned short)bf16_exact((float)(vp[i][j] + 128));
      *(u16x4*)&Vlds[0][dq + j][tb] = pk;
    }
  }
  __syncthreads();
  int cur = 0;

  for (int it = 0; it < nt; ++it) {
    const int t0 = t_begin + (it << 5);
    const bool pf = (it + 1 < nt);

    // ---- issue next tile's global loads (consumed after compute) ----
    i32x4 kp[4], vp[4];
    if (pf) {
      const int* ksrc = kb + (size_t)(t0 + 32 + kt) * Dc + kd;
#pragma unroll
      for (int i = 0; i < 4; ++i) kp[i] = ((const i32x4*)ksrc)[i];
#pragma unroll
      for (int i = 0; i < 4; ++i)
        vp[i] = *(const i32x4*)(vb + (size_t)(t0 + 32 + (tq << 2) + i) * Dc + dq);
    }

    // ---- compute tile from LDS[cur] ----
    const int tA = t0 + l15, tB = t0 + 16 + l15;
    const float ksA = kscb[tA], kzA = kzrb[tA], vsA = vscb[tA], vzA = vzrb[tA];
    const float ksB = kscb[tB], kzB = kzrb[tB], vsB = vscb[tB], vzB = vzrb[tB];

    f32x4 scA = (f32x4){0.f, 0.f, 0.f, 0.f};
    f32x4 scB = (f32x4){0.f, 0.f, 0.f, 0.f};
#pragma unroll
    for (int ks = 0; ks < 4; ++ks) {
      bf16x8 kfA = *(const bf16x8*)
          &Klds[cur][l15][(ks * 32 + (lg << 3)) ^ ((l15 & 7) << 3)];
      scA = __builtin_amdgcn_mfma_f32_16x16x32_bf16(qa[ks], kfA, scA, 0, 0, 0);
    }
#pragma unroll
    for (int ks = 0; ks < 4; ++ks) {
      bf16x8 kfB = *(const bf16x8*)
          &Klds[cur][16 + l15][(ks * 32 + (lg << 3)) ^ ((l15 & 7) << 3)];
      scB = __builtin_amdgcn_mfma_f32_16x16x32_bf16(qa[ks], kfB, scB, 0, 0, 0);
    }

    float s8[2][4];
    const float sclA = ksA * QK_SCALE, kzpA = kzA + 128.f;
    const float sclB = ksB * QK_SCALE, kzpB = kzB + 128.f;
#pragma unroll
    for (int j = 0; j < 4; ++j) {
      s8[0][j] = sclA * (scA[j] - kzpA * qsumc[j]);
      s8[1][j] = sclB * (scB[j] - kzpB * qsumc[j]);
    }

    // one max update + rescale per 32-token tile
    float tm[4];
#pragma unroll
    for (int j = 0; j < 4; ++j) {
      tm[j] = fmaxf(s8[0][j], s8[1][j]);
      tm[j] = fmaxf(tm[j], __shfl_xor(tm[j], 1));
      tm[j] = fmaxf(tm[j], __shfl_xor(tm[j], 2));
      tm[j] = fmaxf(tm[j], __shfl_xor(tm[j], 4));
      tm[j] = fmaxf(tm[j], __shfl_xor(tm[j], 8));
    }
    bool need = false;
    float cf[4];
#pragma unroll
    for (int j = 0; j < 4; ++j) {
      float nm = fmaxf(m[j], tm[j]);
      cf[j] = exp2f(m[j] - nm);
      need = need || (tm[j] > m[j]);
      m[j] = nm;
    }
    if (__any(need)) {
#pragma unroll
      for (int j = 0; j < 4; ++j) { ell[j] *= cf[j]; corr[j] *= cf[j]; }
#pragma unroll
      for (int dt = 0; dt < 8; ++dt)
#pragma unroll
        for (int j = 0; j < 4; ++j) acc[dt][j] *= cf[j];
    }

    // P (consistent with final m), value_scale folded; write Plds
#pragma unroll
    for (int j = 0; j < 4; ++j) {
      float pA = exp2f(s8[0][j] - m[j]);
      float pB = exp2f(s8[1][j] - m[j]);
      ell[j] += pA + pB;
      unsigned short ra = bf16_rne(pA * vsA);
      unsigned short rb = bf16_rne(pB * vsB);
      union { uint32_t u; float ff; } wa{(uint32_t)ra << 16}, wb{(uint32_t)rb << 16};
      corr[j] += wa.ff * (vzA + 128.f) + wb.ff * (vzB + 128.f);
      Plds[wave][(lg << 2) + j][l15]      = ra;
      Plds[wave][(lg << 2) + j][16 + l15] = rb;
    }

    // PV for these 32 tokens
    bf16x8 pa = *(const bf16x8*)&Plds[wave][l15][lg << 3];
#pragma unroll
    for (int dt = 0; dt < 8; ++dt) {
      bf16x8 vbf = *(const bf16x8*)
          &Vlds[cur][(dt << 4) + l15][(lg ^ (dt & 3)) << 3];
      acc[dt] = __builtin_amdgcn_mfma_f32_16x16x32_bf16(pa, vbf, acc[dt], 0, 0, 0);
    }

    // ---- convert + write next tile into LDS[cur^1]; one barrier per tile ----
    if (pf) {
      bf16x8 k0, k1;
#pragma unroll
      for (int j = 0; j < 4; ++j) {
        k0[j]     = bf16_exact((float)(kp[0][j] + 128));
        k0[4 + j] = bf16_exact((float)(kp[1][j] + 128));
        k1[j]     = bf16_exact((float)(kp[2][j] + 128));
        k1[4 + j] = bf16_exact((float)(kp[3][j] + 128));
      }
      *(bf16x8*)&Klds[cur ^ 1][kt][kd ^ ksw]       = k0;
      *(bf16x8*)&Klds[cur ^ 1][kt][(kd + 8) ^ ksw] = k1;
#pragma unroll
      for (int j = 0; j < 4; ++j) {
        u16x4 pk;
#pragma unroll
        for (int i = 0; i < 4; ++i)
          pk[i] = (unsigned short)bf16_exact((float)(vp[i][j] + 128));
        *(u16x4*)&Vlds[cur ^ 1][dq + j][tb] = pk;
      }
      __syncthreads();
      cur ^= 1;
    }
  }

  // ---- final lane reductions over token slots ----
#pragma unroll
  for (int j = 0; j < 4; ++j) {
    ell[j] += __shfl_xor(ell[j], 1);  ell[j] += __shfl_xor(ell[j], 2);
    ell[j] += __shfl_xor(ell[j], 4);  ell[j] += __shfl_xor(ell[j], 8);
    corr[j] += __shfl_xor(corr[j], 1); corr[j] += __shfl_xor(corr[j], 2);
    corr[j] += __shfl_xor(corr[j], 4); corr[j] += __shfl_xor(corr[j], 8);
  }

  const size_t pbase = ((size_t)bg * nsplit + split) * 64;
#pragma unroll
  for (int dt = 0; dt < 8; ++dt)
#pragma unroll
    for (int j = 0; j < 4; ++j) {
      int row = (wave << 4) + (lg << 2) + j;
      int d   = (dt << 4) + l15;
      ws_acc[(pbase + row) * Dc + d] = acc[dt][j] - corr[j];
    }
  if (l15 == 0) {
#pragma unroll
    for (int j = 0; j < 4; ++j) {
      int row = (wave << 4) + (lg << 2) + j;
      ws_m[pbase + row] = m[j];
      ws_l[pbase + row] = ell[j];
    }
  }
}

// ---------------------------------------------------------------------------
// Phase 2: flash-combine partials and normalize. One block per (bg,row).
// ---------------------------------------------------------------------------
__global__ __launch_bounds__(128) void attn_combine(
    const float* __restrict__ ws_acc, const float* __restrict__ ws_m,
    const float* __restrict__ ws_l, float* __restrict__ out, int nsplit)
{
  const int r   = blockIdx.x;      // 0 .. 32*64-1
  const int bg  = r >> 6;
  const int row = r & 63;
  const int d   = threadIdx.x;     // 0..127

  float M = -1e30f;
#pragma unroll 4
  for (int i = 0; i < nsplit; ++i)
    M = fmaxf(M, ws_m[((size_t)bg * nsplit + i) * 64 + row]);
  float L = 0.f, o = 0.f;
#pragma unroll 4
  for (int i = 0; i < nsplit; ++i) {
    size_t pb = ((size_t)bg * nsplit + i) * 64 + row;
    float w = exp2f(ws_m[pb] - M);
    L += ws_l[pb] * w;
    o += ws_acc[pb * Dc + d] * w;
  }
  const int b = bg >> 3, g = bg & 7;
  const int rep = row >> 4, qq = row & 15;
  out[(((size_t)(b * Hc + g * NREPc + rep)) * QLc + qq) * Dc + d] = o / L;
}

extern "C" void kernel_launch(void* const* d_in, const int* in_sizes, int n_in,
                              void* d_out, int out_size, void* d_ws,
                              size_t ws_size, hipStream_t stream) {
  const float* q   = (const float*)d_in[0];
  const int*   kc  = (const int*)d_in[1];   // int8 values promoted to int32
  const int*   vc  = (const int*)d_in[2];
  const float* ksc = (const float*)d_in[3];
  const float* kzr = (const float*)d_in[4];
  const float* vsc = (const float*)d_in[5];
  const float* vzr = (const float*)d_in[6];
  float* out = (float*)d_out;

  int nsplit = 64;                         // 2048 blocks; fallback if ws small
  while (nsplit > 1) {
    size_t need = (size_t)32 * nsplit * 64 * (Dc + 2) * sizeof(float);
    if (need <= ws_size) break;
    nsplit >>= 1;
  }
  float* ws_acc = (float*)d_ws;                             // [32,ns,64,128]
  float* ws_m   = ws_acc + (size_t)32 * nsplit * 64 * Dc;   // [32,ns,64]
  float* ws_l   = ws_m   + (size_t)32 * nsplit * 64;        // [32,ns,64]

  attn_partial<<<dim3(32 * nsplit), dim3(256), 0, stream>>>(
      q, kc, vc, ksc, kzr, vsc, vzr, ws_acc, ws_m, ws_l, nsplit);
  attn_combine<<<dim3(32 * 64), dim3(128), 0, stream>>>(
      ws_acc, ws_m, ws_l, out, nsplit);
}

// Round 8
// 111.671 us; speedup vs baseline: 2.2158x; 1.0108x over previous
//
#include <hip/hip_runtime.h>
#include <hip/hip_bf16.h>
#include <stdint.h>

// Problem constants (CompressedKVAttention_11708080848911)
#define Bc    4
#define Hc    32
#define HKVc  8
#define QLc   16
#define KVc   8192
#define Dc    128
#define NREPc 4   // H / HKV

typedef short bf16x8 __attribute__((ext_vector_type(8)));
typedef float f32x4  __attribute__((ext_vector_type(4)));
typedef int   i32x4  __attribute__((ext_vector_type(4)));
typedef unsigned short u16x4 __attribute__((ext_vector_type(4)));

__device__ __forceinline__ unsigned short bf16_rne(float f) {
  union { float f; uint32_t u; } c{f};
  uint32_t u = c.u + 0x7FFFu + ((c.u >> 16) & 1u);
  return (unsigned short)(u >> 16);
}
// exact for integer-valued floats in [0,255] (low 16 mantissa bits are zero)
__device__ __forceinline__ short bf16_exact(float f) {
  union { float f; uint32_t u; } c{f};
  return (short)(unsigned short)(c.u >> 16);
}

// ---------------------------------------------------------------------------
// Phase 1: per-(b,g,split) flash partials. KV caches arrive as INT32.
// R7 changes (R6 was 117us, latency-bound, hbm 22%, conflicts 4.3M):
//  - Vlds pad restored to 40 cols: R6's 32-col rows made PV ds_read_b128
//    stride 64B -> 16 lanes on one bank-pair = 8-way conflict. 80B rows
//    spread lanes 8 banks -> 2-way (free). (R5 pad removal was the bug.)
//  - SINGLE-buffered K/V LDS (23.5KB, was 37.9KB dbuf) -> 6 blocks/CU LDS cap.
//    Two barriers per tile (read-done, write-visible).
//  - Load issue moved to right after the LDS write consumes the prefetch
//    regs: loads for tile it+2 are in flight across barrier2 + ALL of
//    compute(it+1) (~900+cy window) -> HBM latency fully covered with ONE
//    32-VGPR prefetch set.
// K staged once per block (4 waves share); XOR swizzle col^((row&7)<<3) on
// both write and read. V transposed [d][t^swz], token bits 3..4 XOR (d>>4)&3.
// Swapped-max softmax: one max update per 32-token tile after both halves.
// ---------------------------------------------------------------------------
__global__ __launch_bounds__(256) void attn_partial(
    const float* __restrict__ q, const int* __restrict__ kc,
    const int* __restrict__ vc,
    const float* __restrict__ ksc, const float* __restrict__ kzr,
    const float* __restrict__ vsc, const float* __restrict__ vzr,
    float* __restrict__ ws_acc, float* __restrict__ ws_m,
    float* __restrict__ ws_l, int nsplit)
{
  __shared__ __align__(16) unsigned short Klds[32][128];
  __shared__ __align__(16) unsigned short Vlds[128][40];
  __shared__ __align__(16) unsigned short Plds[4][16][40];

  const int bid   = blockIdx.x;
  const int split = bid % nsplit;
  const int bg    = bid / nsplit;          // 0..31  (= b*HKV + g)
  const int chunk = KVc / nsplit;
  const int t_begin = split * chunk;
  const int nt    = chunk >> 5;            // 32-token tiles

  const int tid  = threadIdx.x;
  const int wave = tid >> 6;
  const int lane = tid & 63;
  const int l15  = lane & 15;
  const int lg   = lane >> 4;              // 0..3

  const int b = bg >> 3, g = bg & 7;
  const int h = (g << 2) + wave;           // this wave's query head

  // ---- Q fragments (bf16) + per-row sum of bf16-rounded Q ----
  bf16x8 qa[4];
  float qsum = 0.f;
  const float* qrow = q + ((size_t)((b * Hc + h) * QLc + l15)) * Dc;
#pragma unroll
  for (int ks = 0; ks < 4; ++ks) {
    const float* p = qrow + ks * 32 + (lg << 3);
    bf16x8 f;
#pragma unroll
    for (int j = 0; j < 8; ++j) {
      unsigned short hb = bf16_rne(p[j]);
      f[j] = (short)hb;
      union { uint32_t u; float ff; } w{(uint32_t)hb << 16};
      qsum += w.ff;                        // sum of post-rounding values
    }
    qa[ks] = f;
  }
  qsum += __shfl_xor(qsum, 16);
  qsum += __shfl_xor(qsum, 32);            // every lane: qsum of row (lane&15)
  float qsumc[4];                          // re-map to C-layout rows 4*lg+j
#pragma unroll
  for (int j = 0; j < 4; ++j) qsumc[j] = __shfl(qsum, (lg << 2) + j);

  const float QK_SCALE = 0.088388347648f * 1.44269504089f; // d^-1/2 * log2(e)

  float m[4], ell[4], corr[4];
  f32x4 acc[8];
#pragma unroll
  for (int j = 0; j < 4; ++j) { m[j] = -1e30f; ell[j] = 0.f; corr[j] = 0.f; }
#pragma unroll
  for (int dt = 0; dt < 8; ++dt) acc[dt] = (f32x4){0.f, 0.f, 0.f, 0.f};

  const int*   kb   = kc  + (size_t)bg * KVc * Dc;
  const int*   vb   = vc  + (size_t)bg * KVc * Dc;
  const float* kscb = ksc + (size_t)bg * KVc;
  const float* kzrb = kzr + (size_t)bg * KVc;
  const float* vscb = vsc + (size_t)bg * KVc;
  const float* vzrb = vzr + (size_t)bg * KVc;

  // staging coords
  const int kt  = tid >> 3;                // K: token 0..31
  const int kd  = (tid & 7) << 4;          // K: d base 0,16,...,112
  const int ksw = (kt & 7) << 3;           // K col swizzle (u16-index XOR)
  const int tq  = tid >> 5;                // V: token group 0..7
  const int dq  = (tid & 31) << 2;         // V: d base 0,4,...,124
  const int tb  = (tq << 2) ^ ((((dq >> 4) & 3)) << 3);  // swizzled col base

  i32x4 kp[4], vp[4];                      // prefetch registers (one set)

  // ---- prologue: load+write tile 0, then issue tile 1 ----
  {
    const int* ksrc = kb + (size_t)(t_begin + kt) * Dc + kd;
#pragma unroll
    for (int i = 0; i < 4; ++i) kp[i] = ((const i32x4*)ksrc)[i];
#pragma unroll
    for (int i = 0; i < 4; ++i)
      vp[i] = *(const i32x4*)(vb + (size_t)(t_begin + (tq << 2) + i) * Dc + dq);

    bf16x8 k0, k1;
#pragma unroll
    for (int j = 0; j < 4; ++j) {
      k0[j]     = bf16_exact((float)(kp[0][j] + 128));
      k0[4 + j] = bf16_exact((float)(kp[1][j] + 128));
      k1[j]     = bf16_exact((float)(kp[2][j] + 128));
      k1[4 + j] = bf16_exact((float)(kp[3][j] + 128));
    }
    *(bf16x8*)&Klds[kt][kd ^ ksw]       = k0;
    *(bf16x8*)&Klds[kt][(kd + 8) ^ ksw] = k1;
#pragma unroll
    for (int j = 0; j < 4; ++j) {
      u16x4 pk;
#pragma unroll
      for (int i = 0; i < 4; ++i)
        pk[i] = (unsigned short)bf16_exact((float)(vp[i][j] + 128));
      *(u16x4*)&Vlds[dq + j][tb] = pk;
    }
    if (nt > 1) {
      const int* ksrc1 = kb + (size_t)(t_begin + 32 + kt) * Dc + kd;
#pragma unroll
      for (int i = 0; i < 4; ++i) kp[i] = ((const i32x4*)ksrc1)[i];
#pragma unroll
      for (int i = 0; i < 4; ++i)
        vp[i] = *(const i32x4*)(vb + (size_t)(t_begin + 32 + (tq << 2) + i) * Dc + dq);
    }
  }
  __syncthreads();

  for (int it = 0; it < nt; ++it) {
    const int t0 = t_begin + (it << 5);

    // ---- compute tile from LDS (loads for it+1 in flight) ----
    const int tA = t0 + l15, tB = t0 + 16 + l15;
    const float ksA = kscb[tA], kzA = kzrb[tA], vsA = vscb[tA], vzA = vzrb[tA];
    const float ksB = kscb[tB], kzB = kzrb[tB], vsB = vscb[tB], vzB = vzrb[tB];

    f32x4 scA = (f32x4){0.f, 0.f, 0.f, 0.f};
    f32x4 scB = (f32x4){0.f, 0.f, 0.f, 0.f};
#pragma unroll
    for (int ks = 0; ks < 4; ++ks) {
      bf16x8 kfA = *(const bf16x8*)
          &Klds[l15][(ks * 32 + (lg << 3)) ^ ((l15 & 7) << 3)];
      scA = __builtin_amdgcn_mfma_f32_16x16x32_bf16(qa[ks], kfA, scA, 0, 0, 0);
    }
#pragma unroll
    for (int ks = 0; ks < 4; ++ks) {
      bf16x8 kfB = *(const bf16x8*)
          &Klds[16 + l15][(ks * 32 + (lg << 3)) ^ ((l15 & 7) << 3)];
      scB = __builtin_amdgcn_mfma_f32_16x16x32_bf16(qa[ks], kfB, scB, 0, 0, 0);
    }

    float s8[2][4];
    const float sclA = ksA * QK_SCALE, kzpA = kzA + 128.f;
    const float sclB = ksB * QK_SCALE, kzpB = kzB + 128.f;
#pragma unroll
    for (int j = 0; j < 4; ++j) {
      s8[0][j] = sclA * (scA[j] - kzpA * qsumc[j]);
      s8[1][j] = sclB * (scB[j] - kzpB * qsumc[j]);
    }

    // one max update + rescale per 32-token tile
    float tm[4];
#pragma unroll
    for (int j = 0; j < 4; ++j) {
      tm[j] = fmaxf(s8[0][j], s8[1][j]);
      tm[j] = fmaxf(tm[j], __shfl_xor(tm[j], 1));
      tm[j] = fmaxf(tm[j], __shfl_xor(tm[j], 2));
      tm[j] = fmaxf(tm[j], __shfl_xor(tm[j], 4));
      tm[j] = fmaxf(tm[j], __shfl_xor(tm[j], 8));
    }
    bool need = false;
    float cf[4];
#pragma unroll
    for (int j = 0; j < 4; ++j) {
      float nm = fmaxf(m[j], tm[j]);
      cf[j] = exp2f(m[j] - nm);
      need = need || (tm[j] > m[j]);
      m[j] = nm;
    }
    if (__any(need)) {
#pragma unroll
      for (int j = 0; j < 4; ++j) { ell[j] *= cf[j]; corr[j] *= cf[j]; }
#pragma unroll
      for (int dt = 0; dt < 8; ++dt)
#pragma unroll
        for (int j = 0; j < 4; ++j) acc[dt][j] *= cf[j];
    }

    // P (consistent with final m), value_scale folded; write Plds (wave-private)
#pragma unroll
    for (int j = 0; j < 4; ++j) {
      float pA = exp2f(s8[0][j] - m[j]);
      float pB = exp2f(s8[1][j] - m[j]);
      ell[j] += pA + pB;
      unsigned short ra = bf16_rne(pA * vsA);
      unsigned short rb = bf16_rne(pB * vsB);
      union { uint32_t u; float ff; } wa{(uint32_t)ra << 16}, wb{(uint32_t)rb << 16};
      corr[j] += wa.ff * (vzA + 128.f) + wb.ff * (vzB + 128.f);
      Plds[wave][(lg << 2) + j][l15]      = ra;
      Plds[wave][(lg << 2) + j][16 + l15] = rb;
    }

    // PV for these 32 tokens
    bf16x8 pa = *(const bf16x8*)&Plds[wave][l15][lg << 3];
#pragma unroll
    for (int dt = 0; dt < 8; ++dt) {
      bf16x8 vbf = *(const bf16x8*)
          &Vlds[(dt << 4) + l15][(lg ^ (dt & 3)) << 3];
      acc[dt] = __builtin_amdgcn_mfma_f32_16x16x32_bf16(pa, vbf, acc[dt], 0, 0, 0);
    }

    // ---- single-buffer swap: write it+1, issue it+2 ----
    if (it + 1 < nt) {
      __syncthreads();                     // everyone done READING K/V
      bf16x8 k0, k1;
#pragma unroll
      for (int j = 0; j < 4; ++j) {        // vmcnt drain for kp/vp here
        k0[j]     = bf16_exact((float)(kp[0][j] + 128));
        k0[4 + j] = bf16_exact((float)(kp[1][j] + 128));
        k1[j]     = bf16_exact((float)(kp[2][j] + 128));
        k1[4 + j] = bf16_exact((float)(kp[3][j] + 128));
      }
      *(bf16x8*)&Klds[kt][kd ^ ksw]       = k0;
      *(bf16x8*)&Klds[kt][(kd + 8) ^ ksw] = k1;
#pragma unroll
      for (int j = 0; j < 4; ++j) {
        u16x4 pk;
#pragma unroll
        for (int i = 0; i < 4; ++i)
          pk[i] = (unsigned short)bf16_exact((float)(vp[i][j] + 128));
        *(u16x4*)&Vlds[dq + j][tb] = pk;
      }
      if (it + 2 < nt) {                   // re-issue into freed regs:
        const int tn = t0 + 64;            // in flight across barrier+compute
        const int* ksrc = kb + (size_t)(tn + kt) * Dc + kd;
#pragma unroll
        for (int i = 0; i < 4; ++i) kp[i] = ((const i32x4*)ksrc)[i];
#pragma unroll
        for (int i = 0; i < 4; ++i)
          vp[i] = *(const i32x4*)(vb + (size_t)(tn + (tq << 2) + i) * Dc + dq);
      }
      __syncthreads();                     // writes visible
    }
  }

  // ---- final lane reductions over token slots ----
#pragma unroll
  for (int j = 0; j < 4; ++j) {
    ell[j] += __shfl_xor(ell[j], 1);  ell[j] += __shfl_xor(ell[j], 2);
    ell[j] += __shfl_xor(ell[j], 4);  ell[j] += __shfl_xor(ell[j], 8);
    corr[j] += __shfl_xor(corr[j], 1); corr[j] += __shfl_xor(corr[j], 2);
    corr[j] += __shfl_xor(corr[j], 4); corr[j] += __shfl_xor(corr[j], 8);
  }

  const size_t pbase = ((size_t)bg * nsplit + split) * 64;
#pragma unroll
  for (int dt = 0; dt < 8; ++dt)
#pragma unroll
    for (int j = 0; j < 4; ++j) {
      int row = (wave << 4) + (lg << 2) + j;
      int d   = (dt << 4) + l15;
      ws_acc[(pbase + row) * Dc + d] = acc[dt][j] - corr[j];
    }
  if (l15 == 0) {
#pragma unroll
    for (int j = 0; j < 4; ++j) {
      int row = (wave << 4) + (lg << 2) + j;
      ws_m[pbase + row] = m[j];
      ws_l[pbase + row] = ell[j];
    }
  }
}

// ---------------------------------------------------------------------------
// Phase 2: flash-combine partials and normalize. One block per (bg,row).
// ---------------------------------------------------------------------------
__global__ __launch_bounds__(128) void attn_combine(
    const float* __restrict__ ws_acc, const float* __restrict__ ws_m,
    const float* __restrict__ ws_l, float* __restrict__ out, int nsplit)
{
  const int r   = blockIdx.x;      // 0 .. 32*64-1
  const int bg  = r >> 6;
  const int row = r & 63;
  const int d   = threadIdx.x;     // 0..127

  float M = -1e30f;
#pragma unroll 4
  for (int i = 0; i < nsplit; ++i)
    M = fmaxf(M, ws_m[((size_t)bg * nsplit + i) * 64 + row]);
  float L = 0.f, o = 0.f;
#pragma unroll 4
  for (int i = 0; i < nsplit; ++i) {
    size_t pb = ((size_t)bg * nsplit + i) * 64 + row;
    float w = exp2f(ws_m[pb] - M);
    L += ws_l[pb] * w;
    o += ws_acc[pb * Dc + d] * w;
  }
  const int b = bg >> 3, g = bg & 7;
  const int rep = row >> 4, qq = row & 15;
  out[(((size_t)(b * Hc + g * NREPc + rep)) * QLc + qq) * Dc + d] = o / L;
}

extern "C" void kernel_launch(void* const* d_in, const int* in_sizes, int n_in,
                              void* d_out, int out_size, void* d_ws,
                              size_t ws_size, hipStream_t stream) {
  const float* q   = (const float*)d_in[0];
  const int*   kc  = (const int*)d_in[1];   // int8 values promoted to int32
  const int*   vc  = (const int*)d_in[2];
  const float* ksc = (const float*)d_in[3];
  const float* kzr = (const float*)d_in[4];
  const float* vsc = (const float*)d_in[5];
  const float* vzr = (const float*)d_in[6];
  float* out = (float*)d_out;

  int nsplit = 64;                         // 2048 blocks; fallback if ws small
  while (nsplit > 1) {
    size_t need = (size_t)32 * nsplit * 64 * (Dc + 2) * sizeof(float);
    if (need <= ws_size) break;
    nsplit >>= 1;
  }
  float* ws_acc = (float*)d_ws;                             // [32,ns,64,128]
  float* ws_m   = ws_acc + (size_t)32 * nsplit * 64 * Dc;   // [32,ns,64]
  float* ws_l   = ws_m   + (size_t)32 * nsplit * 64;        // [32,ns,64]

  attn_partial<<<dim3(32 * nsplit), dim3(256), 0, stream>>>(
      q, kc, vc, ksc, kzr, vsc, vzr, ws_acc, ws_m, ws_l, nsplit);
  attn_combine<<<dim3(32 * 64), dim3(128), 0, stream>>>(
      ws_acc, ws_m, ws_l, out, nsplit);
}